// Round 8
// baseline (439.603 us; speedup 1.0000x reference)
//
#include <hip/hip_runtime.h>
#include <hip/hip_bf16.h>
#include <stdint.h>

typedef __attribute__((ext_vector_type(4))) float f32x4;
typedef __attribute__((ext_vector_type(8))) short s16x8;
typedef __attribute__((ext_vector_type(4))) short s16x4;
typedef __attribute__((ext_vector_type(8))) unsigned short u16x8;

#define NB 8
#define HH 56
#define WW0 56
#define NC 384
#define NQTOK (HH*WW0)     // 3136
#define NKTOK 784
#define NHEAD 6
#define HDIM 64
// scale folded into q-conv: (1/sqrt(64)) * log2(e)
#define QSCALE 0.18033688f

__device__ __forceinline__ float bf2f(unsigned short u) {
    union { unsigned int i; float f; } x; x.i = ((unsigned int)u) << 16; return x.f;
}
__device__ __forceinline__ unsigned short f2bf(float f) {
    union { float f; unsigned int i; } x; x.f = f;
    unsigned int r = x.i + 0x7FFFu + ((x.i >> 16) & 1u);
    return (unsigned short)(r >> 16);
}
__device__ __forceinline__ short f2bf_hw(float f) {
    __hip_bfloat16 hb = __float2bfloat16(f);
    return *reinterpret_cast<short*>(&hb);
}
__device__ __forceinline__ unsigned int cvtpk(float lo, float hi) {
    unsigned int r;
    asm("v_cvt_pk_bf16_f32 %0, %1, %2" : "=v"(r) : "v"(lo), "v"(hi));
    return r;
}
struct PB4 { union { unsigned int u[2]; s16x4 v; }; };

// ---------- prep kernels ----------
__global__ __launch_bounds__(256) void cvt_bf16(const float* __restrict__ src,
                                                unsigned short* __restrict__ dst, int n8) {
    int i = blockIdx.x*256 + threadIdx.x;
    if (i >= n8) return;
    f32x4 a0 = *(const f32x4*)&src[(size_t)i*8];
    f32x4 a1 = *(const f32x4*)&src[(size_t)i*8 + 4];
    u16x8 p;
    #pragma unroll
    for (int j = 0; j < 4; ++j) { p[j] = f2bf(a0[j]); p[j+4] = f2bf(a1[j]); }
    *(u16x8*)&dst[(size_t)i*8] = p;
}

__global__ __launch_bounds__(256) void cvt_w4(
    const float* __restrict__ a, const float* __restrict__ b,
    const float* __restrict__ c, const float* __restrict__ d,
    unsigned short* __restrict__ dst) {
    int i = blockIdx.x*256 + threadIdx.x;              // 73728 = 4*147456/8
    if (i >= 73728) return;
    int m = i / 18432;
    const float* s = (m==0) ? a : ((m==1) ? b : ((m==2) ? c : d));
    int r = i - m*18432;
    f32x4 a0 = *(const f32x4*)&s[(size_t)r*8];
    f32x4 a1 = *(const f32x4*)&s[(size_t)r*8 + 4];
    u16x8 p;
    #pragma unroll
    for (int j = 0; j < 4; ++j) { p[j] = f2bf(a0[j]); p[j+4] = f2bf(a1[j]); }
    *(u16x8*)&dst[(size_t)i*8] = p;
}

__global__ __launch_bounds__(256) void cvt_bias(
    const float* __restrict__ a, const float* __restrict__ b,
    const float* __restrict__ c, const float* __restrict__ d,
    float* __restrict__ dst) {
    int i = blockIdx.x*256 + threadIdx.x;
    if (i >= 4*NC) return;
    int m = i / NC, r = i - m*NC;
    dst[i] = ((m==0) ? a : ((m==1) ? b : ((m==2) ? c : d)))[r];
}

__global__ __launch_bounds__(256) void prep_w(
    const float* __restrict__ qw, const float* __restrict__ kw, const float* __restrict__ vw,
    float* __restrict__ wt)   // [3][9][NC]
{
    int i = blockIdx.x*256 + threadIdx.x;
    if (i >= 3*9*NC) return;
    int m = i / (9*NC); int r = i - m*(9*NC);
    int tap = r / NC; int c = r - tap*NC;
    const float* src = (m==0) ? qw : ((m==1) ? kw : vw);
    wt[i] = src[c*9 + tap];
}

// ---------- GEMM (pure bf16 operands, XOR-swizzled LDS) ----------
template<bool OUT_F32>
__global__ __launch_bounds__(256) void gemm_bt_bf(
    const unsigned short* __restrict__ A,
    const unsigned short* __restrict__ Wall,  // [nmat][384*384] bf16
    const float* __restrict__ Ball,           // [nmat][384] f32
    unsigned short* __restrict__ Oa, unsigned short* __restrict__ Ob, unsigned short* __restrict__ Oc,
    float* __restrict__ Of,
    int ntiles)
{
    __shared__ unsigned short lA[128*64];
    __shared__ unsigned short lW[128*64];
    char* lAb = (char*)lA;
    char* lWb = (char*)lW;
    const int bid = blockIdx.x;
    const int nt = bid % ntiles;
    const int mt = bid / ntiles;
    const int mat = nt / 3;
    const int ncol = nt - mat*3;
    const unsigned short* W = Wall + (size_t)mat*NC*NC;
    const float* Bsel = Ball + mat*NC;
    unsigned short* Osel = (mat==0) ? Oa : ((mat==1) ? Ob : Oc);
    const int Mbase = mt*128, Nbase = ncol*128;
    const int t = threadIdx.x;
    const int w = t >> 6, l = t & 63;
    const int wr = w >> 1, wc = w & 1;
    const int lr = l & 15, lg = l >> 4;
    const int swg = (lr & 7) << 4;

    f32x4 acc[4][4] = {};
    for (int kt = 0; kt < 6; ++kt) {
        __syncthreads();
        #pragma unroll
        for (int i = 0; i < 4; ++i) {
            int c = i*256 + t;
            int row = c >> 3, c8 = c & 7;
            int sdst = row*128 + ((c8*16) ^ ((row & 7) << 4));
            *(u16x8*)(lAb + sdst) = *(const u16x8*)&A[(size_t)(Mbase+row)*NC + kt*64 + c8*8];
            *(u16x8*)(lWb + sdst) = *(const u16x8*)&W[(size_t)(Nbase+row)*NC + kt*64 + c8*8];
        }
        __syncthreads();
        #pragma unroll
        for (int kk = 0; kk < 2; ++kk) {
            s16x8 af[4], bfr[4];
            #pragma unroll
            for (int m = 0; m < 4; ++m)
                af[m] = *(const s16x8*)(lAb + (wr*64 + m*16 + lr)*128 + ((kk*64 + lg*16) ^ swg));
            #pragma unroll
            for (int n = 0; n < 4; ++n)
                bfr[n] = *(const s16x8*)(lWb + (wc*64 + n*16 + lr)*128 + ((kk*64 + lg*16) ^ swg));
            #pragma unroll
            for (int m = 0; m < 4; ++m)
                #pragma unroll
                for (int n = 0; n < 4; ++n)
                    acc[m][n] = __builtin_amdgcn_mfma_f32_16x16x32_bf16(af[m], bfr[n], acc[m][n], 0, 0, 0);
        }
    }
    #pragma unroll
    for (int n = 0; n < 4; ++n) {
        int col = Nbase + wc*64 + n*16 + lr;
        float bias = Bsel[col];
        #pragma unroll
        for (int m = 0; m < 4; ++m) {
            int row0 = Mbase + wr*64 + m*16 + lg*4;
            #pragma unroll
            for (int r = 0; r < 4; ++r) {
                float vv = acc[m][n][r] + bias;
                if (OUT_F32) Of[(size_t)(row0 + r)*NC + col] = vv;
                else Osel[(size_t)(row0 + r)*NC + col] = f2bf(vv);
            }
        }
    }
}

// ---------- depthwise conv ----------
// MODE: 0 = token layout (b,tok,384); 1 = head-packed K (bh,tok,64); 2 = transposed V (bh,d,tok)
template<int S, int HO, int WO, bool SCALE, int MODE>
__global__ __launch_bounds__(256) void dwconv(
    const unsigned short* __restrict__ in,
    const float* __restrict__ wt9,   // (9, NC) transposed
    const float* __restrict__ bias,  // (NC)
    unsigned short* __restrict__ outp)
{
    const int nc8 = NC/8;
    int idx = blockIdx.x*256 + threadIdx.x;
    if (idx >= NB*HO*WO*nc8) return;
    int c8 = idx % nc8; int rest = idx / nc8;
    int wo = rest % WO; rest /= WO;
    int ho = rest % HO; int b = rest / HO;
    int c0 = c8*8;
    f32x4 b0 = *(const f32x4*)&bias[c0];
    f32x4 b1 = *(const f32x4*)&bias[c0+4];
    float acc[8];
    #pragma unroll
    for (int j = 0; j < 4; ++j) { acc[j] = b0[j]; acc[j+4] = b1[j]; }
    #pragma unroll
    for (int kh = 0; kh < 3; ++kh) {
        int h = ho*S + kh - 1;
        if (h < 0 || h >= HH) continue;
        #pragma unroll
        for (int kw = 0; kw < 3; ++kw) {
            int ww = wo*S + kw - 1;
            if (ww < 0 || ww >= WW0) continue;
            int tap = kh*3 + kw;
            u16x8 xv = *(const u16x8*)&in[((size_t)b*(HH*WW0) + h*WW0 + ww)*NC + c0];
            f32x4 w0 = *(const f32x4*)&wt9[tap*NC + c0];
            f32x4 w1 = *(const f32x4*)&wt9[tap*NC + c0 + 4];
            #pragma unroll
            for (int j = 0; j < 4; ++j) {
                acc[j]   += bf2f(xv[j])   * w0[j];
                acc[j+4] += bf2f(xv[j+4]) * w1[j];
            }
        }
    }
    if (SCALE) {
        #pragma unroll
        for (int j = 0; j < 8; ++j) acc[j] *= QSCALE;
    }
    int tok = ho*WO + wo;
    int hh = c0 >> 6, d0 = c0 & 63;
    if (MODE == 0) {
        u16x8 ov;
        #pragma unroll
        for (int j = 0; j < 8; ++j) ov[j] = f2bf(acc[j]);
        *(u16x8*)&outp[((size_t)b*(HO*WO) + tok)*NC + c0] = ov;
    } else if (MODE == 1) {
        u16x8 ov;
        #pragma unroll
        for (int j = 0; j < 8; ++j) ov[j] = f2bf(acc[j]);
        *(u16x8*)&outp[((size_t)(b*NHEAD + hh)*(HO*WO) + tok)*HDIM + d0] = ov;
    } else {
        size_t base = ((size_t)(b*NHEAD + hh)*HDIM + d0)*(HO*WO) + tok;
        #pragma unroll
        for (int j = 0; j < 8; ++j)
            outp[base + (size_t)j*(HO*WO)] = f2bf(acc[j]);
    }
}

// ---------- attention ----------
// sign(s)*softmax(|s|), no max tracking, per-lane deferred denominator.
// KVBLK=128 (2 x 64 subtiles, T15-lite interleave: QK_B overlaps SM_A, PV_A overlaps SM_B),
// double-buffered 64KB LDS, compile-time buffer offsets, cvt_pk P-packing, no setprio.
__global__ __launch_bounds__(512, 4) void attn_fwd(
    const unsigned short* __restrict__ Q,   // (NB, 3136, 384) bf16 pre-scaled by 0.125*log2e
    const unsigned short* __restrict__ Kpk, // (48, 784, 64) bf16 head-packed
    const unsigned short* __restrict__ Vt,  // (48, 64, 784) bf16 transposed
    unsigned short* __restrict__ ctx)       // (NB, 3136, 384) bf16
{
    __shared__ unsigned short lK[2][8192];  // [buf][128 tok x 64 d]
    __shared__ unsigned short lV[2][8192];  // [buf][64 d x 128 tok]
    const int bid = blockIdx.x;             // 624 = 8 XCD * 6 bh * 13 qt
    const int xcd = bid & 7, slot = bid >> 3;
    const int bh = xcd*6 + slot/13;
    const int qt = slot % 13;
    const int b = bh / NHEAD, h = bh - b*NHEAD;
    const int t = threadIdx.x;
    const int w = t >> 6, l = t & 63;
    const int lq = l & 15, lg = l >> 4;
    const int wq0 = qt*256 + w*32;
    const int wq0c = (wq0 > NQTOK-32) ? (NQTOK-32) : wq0;

    const unsigned short* Qb = Q + ((size_t)b*NQTOK + wq0c + lq)*NC + h*HDIM;
    s16x8 qA00 = *(const s16x8*)&Qb[lg*8];
    s16x8 qA01 = *(const s16x8*)&Qb[32 + lg*8];
    s16x8 qA10 = *(const s16x8*)&Qb[16*NC + lg*8];
    s16x8 qA11 = *(const s16x8*)&Qb[16*NC + 32 + lg*8];

    const char* Kg = (const char*)(Kpk + (size_t)bh*NKTOK*HDIM);
    const char* Vg = (const char*)(Vt + (size_t)bh*HDIM*NKTOK);
    char* lKb = (char*)&lK[0][0];
    char* lVb = (char*)&lV[0][0];

    // staging: K tile 1024 x 16B chunks, V tile 1024 x 16B chunks; 2 each per thread
    const int c0i = t, c1i = t + 512;
    const int kr0 = c0i >> 3, kc0 = (c0i & 7) << 4;
    const int kr1 = c1i >> 3, kc1 = (c1i & 7) << 4;
    const int kd0 = kr0*128 + (kc0 ^ ((kr0 & 7) << 4));
    const int kd1 = kr1*128 + (kc1 ^ ((kr1 & 7) << 4));
    const int vr0 = c0i >> 4, vc0 = (c0i & 15) << 4;
    const int vr1 = c1i >> 4, vc1 = (c1i & 15) << 4;
    const int vd0 = vr0*256 + (vc0 ^ ((vr0 & 7) << 4));
    const int vd1 = vr1*256 + (vc1 ^ ((vr1 & 7) << 4));

    uint4 rk0, rk1, rv0, rv1;
    #define LOADT(kb) do { \
        rk0 = *(const uint4*)(Kg + (size_t)((kb) + kr0)*128 + kc0); \
        rk1 = *(const uint4*)(Kg + (size_t)((kb) + kr1)*128 + kc1); \
        rv0 = *(const uint4*)(Vg + (size_t)vr0*1568 + (kb)*2 + vc0); \
        rv1 = *(const uint4*)(Vg + (size_t)vr1*1568 + (kb)*2 + vc1); \
    } while(0)
    #define WRITET(buf) do { \
        *(uint4*)(lKb + (buf)*16384 + kd0) = rk0; \
        *(uint4*)(lKb + (buf)*16384 + kd1) = rk1; \
        *(uint4*)(lVb + (buf)*16384 + vd0) = rv0; \
        *(uint4*)(lVb + (buf)*16384 + vd1) = rv1; \
    } while(0)

    // per-lane read bases
    const int swc = (lq & 7) << 4;
    const int kb0 = lq*128 + ((lg*16) ^ swc);
    const int kb1 = lq*128 + ((64 + lg*16) ^ swc);
    const int vbase = lq*256 + ((lg*8) ^ swc);

    float ls[2] = {0.f, 0.f};
    f32x4 oacc[2][4] = {};

    #define QK4(ST, KOFF) \
        _Pragma("unroll") \
        for (int j = 0; j < 4; ++j) { \
            s16x8 kf0 = *(const s16x8*)(lKb + (KOFF) + j*2048 + kb0); \
            s16x8 kf1 = *(const s16x8*)(lKb + (KOFF) + j*2048 + kb1); \
            ST[0][j] = __builtin_amdgcn_mfma_f32_16x16x32_bf16(kf0, qA00, ST[0][j], 0,0,0); \
            ST[0][j] = __builtin_amdgcn_mfma_f32_16x16x32_bf16(kf1, qA01, ST[0][j], 0,0,0); \
            ST[1][j] = __builtin_amdgcn_mfma_f32_16x16x32_bf16(kf0, qA10, ST[1][j], 0,0,0); \
            ST[1][j] = __builtin_amdgcn_mfma_f32_16x16x32_bf16(kf1, qA11, ST[1][j], 0,0,0); \
        }
    #define SM4(ST, PB) \
        _Pragma("unroll") \
        for (int qf = 0; qf < 2; ++qf) { \
            float rs = 0.f; \
            _Pragma("unroll") \
            for (int j = 0; j < 4; ++j) { \
                float p[4]; \
                _Pragma("unroll") \
                for (int r = 0; r < 4; ++r) { \
                    float s = ST[qf][j][r]; \
                    float e = exp2f(fabsf(s)); \
                    rs += e; \
                    p[r] = copysignf(e, s); \
                } \
                PB[qf][j].u[0] = cvtpk(p[0], p[1]); \
                PB[qf][j].u[1] = cvtpk(p[2], p[3]); \
            } \
            ls[qf] += rs; \
        }
    #define PV4(PB, VOFF, KSB) \
        _Pragma("unroll") \
        for (int ks = 0; ks < 4; ++ks) { \
            const int vx = vbase ^ (((KSB) + ks)*32); \
            _Pragma("unroll") \
            for (int f = 0; f < 4; ++f) { \
                s16x4 vvf = *(const s16x4*)(lVb + (VOFF) + f*4096 + vx); \
                oacc[0][f] = __builtin_amdgcn_mfma_f32_16x16x16bf16_1k(vvf, PB[0][ks].v, oacc[0][f], 0,0,0); \
                oacc[1][f] = __builtin_amdgcn_mfma_f32_16x16x16bf16_1k(vvf, PB[1][ks].v, oacc[1][f], 0,0,0); \
            } \
        }
    #define BODY(BUF, KT) do { \
        f32x4 stA[2][4] = {}; \
        QK4(stA, (BUF)*16384); \
        PB4 pbA[2][4]; \
        SM4(stA, pbA); \
        f32x4 stB[2][4] = {}; \
        QK4(stB, (BUF)*16384 + 8192); \
        if ((KT) < 5) LOADT(((KT)+1)*128); \
        PV4(pbA, (BUF)*16384, 0); \
        PB4 pbB[2][4]; \
        SM4(stB, pbB); \
        PV4(pbB, (BUF)*16384, 4); \
        if ((KT) < 5) { WRITET((BUF)^1); __syncthreads(); } \
    } while(0)

    LOADT(0);
    WRITET(0);
    __syncthreads();

    for (int kt2 = 0; kt2 < 3; ++kt2) {
        BODY(0, kt2*2);
        BODY(1, kt2*2 + 1);
    }

    // tail: k = 768..783 direct from global
    {
        const unsigned short* Kb2 = (const unsigned short*)Kg;
        const unsigned short* Vb2 = (const unsigned short*)Vg;
        const unsigned short* kr = &Kb2[(size_t)(768 + lq)*HDIM];
        s16x8 kf0 = *(const s16x8*)&kr[lg*8];
        s16x8 kf1 = *(const s16x8*)&kr[32 + lg*8];
        f32x4 st[2] = {};
        st[0] = __builtin_amdgcn_mfma_f32_16x16x32_bf16(kf0, qA00, st[0], 0,0,0);
        st[0] = __builtin_amdgcn_mfma_f32_16x16x32_bf16(kf1, qA01, st[0], 0,0,0);
        st[1] = __builtin_amdgcn_mfma_f32_16x16x32_bf16(kf0, qA10, st[1], 0,0,0);
        st[1] = __builtin_amdgcn_mfma_f32_16x16x32_bf16(kf1, qA11, st[1], 0,0,0);
        s16x4 vv[4];
        #pragma unroll
        for (int f = 0; f < 4; ++f)
            vv[f] = *(const s16x4*)&Vb2[(size_t)(f*16 + lq)*NKTOK + 768 + lg*4];
        PB4 pbv[2];
        #pragma unroll
        for (int qf = 0; qf < 2; ++qf) {
            float rs = 0.f, p[4];
            #pragma unroll
            for (int r = 0; r < 4; ++r) {
                float s = st[qf][r];
                float e = exp2f(fabsf(s));
                rs += e;
                p[r] = copysignf(e, s);
            }
            pbv[qf].u[0] = cvtpk(p[0], p[1]);
            pbv[qf].u[1] = cvtpk(p[2], p[3]);
            ls[qf] += rs;
        }
        #pragma unroll
        for (int f = 0; f < 4; ++f) {
            oacc[0][f] = __builtin_amdgcn_mfma_f32_16x16x16bf16_1k(vv[f], pbv[0].v, oacc[0][f], 0,0,0);
            oacc[1][f] = __builtin_amdgcn_mfma_f32_16x16x16bf16_1k(vv[f], pbv[1].v, oacc[1][f], 0,0,0);
        }
    }
    if (wq0 < NQTOK) {
        #pragma unroll
        for (int qf = 0; qf < 2; ++qf) {
            float lr2 = ls[qf];
            lr2 += __shfl_xor(lr2, 16);
            lr2 += __shfl_xor(lr2, 32);
            float inv = 1.f / lr2;
            unsigned short* cb = ctx + ((size_t)b*NQTOK + wq0 + qf*16 + lq)*NC + h*HDIM;
            #pragma unroll
            for (int f = 0; f < 4; ++f) {
                s16x4 o;
                #pragma unroll
                for (int r = 0; r < 4; ++r) o[r] = f2bf_hw(oacc[qf][f][r] * inv);
                *(s16x4*)&cb[f*16 + lg*4] = o;
            }
        }
    }
    #undef LOADT
    #undef WRITET
    #undef QK4
    #undef SM4
    #undef PV4
    #undef BODY
}

extern "C" void kernel_launch(void* const* d_in, const int* in_sizes, int n_in,
                              void* d_out, int out_size, void* d_ws, size_t ws_size,
                              hipStream_t stream)
{
    (void)in_sizes; (void)n_in; (void)out_size; (void)ws_size;
    const float* x      = (const float*)d_in[0];
    const float* q_w    = (const float*)d_in[3];
    const float* q_b    = (const float*)d_in[4];
    const float* k_w    = (const float*)d_in[5];
    const float* k_b    = (const float*)d_in[6];
    const float* v_w    = (const float*)d_in[7];
    const float* v_b    = (const float*)d_in[8];
    const float* q_dw_w = (const float*)d_in[9];
    const float* q_dw_b = (const float*)d_in[10];
    const float* k_dw_w = (const float*)d_in[11];
    const float* k_dw_b = (const float*)d_in[12];
    const float* v_dw_w = (const float*)d_in[13];
    const float* v_dw_b = (const float*)d_in[14];
    const float* proj_w = (const float*)d_in[15];
    const float* proj_b = (const float*)d_in[16];
    float* outf = (float*)d_out;
    unsigned short* ws  = (unsigned short*)d_ws;

    const size_t nQ  = (size_t)NB*NQTOK*NC;   // 9,633,792 elems
    const size_t nKc = (size_t)NB*NKTOK*NC;   // 2,408,448 elems
    unsigned short* preQ = ws;                // bf16 pre-conv Q
    unsigned short* preK = ws + nQ;           // bf16 pre-conv K; later ctx
    unsigned short* Kpk  = ws + 2*nQ;         // bf16 post-conv K, head-packed (bh,k,64)
    unsigned short* Vt   = Kpk + nKc;         // bf16 post-conv V, transposed (bh,d,k)
    unsigned short* wbf  = Vt + nKc;          // bf16 [4][384*384] dense weights
    float* wtab = (float*)(wbf + (size_t)4*NC*NC);   // [3][9][384] dw weights transposed
    float* ball = wtab + 3*9*NC;              // [4][384] biases
    unsigned short* preV = (unsigned short*)d_out;          // d_out lower half
    unsigned short* Qc   = (unsigned short*)d_out;          // after preV consumed
    unsigned short* xbf  = ((unsigned short*)d_out) + nQ;   // d_out upper half: bf16 x
    unsigned short* ctx  = preK;              // reuse preK after k-conv

    // 0. prep: dtype conversions + weight transposes
    cvt_bf16<<<dim3(4704), dim3(256), 0, stream>>>(x, xbf, (int)(nQ/8));
    cvt_w4  <<<dim3(288),  dim3(256), 0, stream>>>(q_w, k_w, v_w, proj_w, wbf);
    cvt_bias<<<dim3(6),    dim3(256), 0, stream>>>(q_b, k_b, v_b, proj_b, ball);
    prep_w  <<<dim3(41),   dim3(256), 0, stream>>>(q_dw_w, k_dw_w, v_dw_w, wtab);
    // 1. QKV projections (bf16 x bf16): Q->preQ, K->preK, V->preV(d_out)
    gemm_bt_bf<false><<<dim3(196*9), dim3(256), 0, stream>>>(
        xbf, wbf, ball, preQ, preK, preV, nullptr, 9);
    // 2. depthwise convs; K head-packed, V transposed, Q scaled by 0.125*log2e
    dwconv<2,28,28,false,1><<<dim3(1176), dim3(256), 0, stream>>>(preK, wtab + 1*9*NC, k_dw_b, Kpk);
    dwconv<2,28,28,false,2><<<dim3(1176), dim3(256), 0, stream>>>(preV, wtab + 2*9*NC, v_dw_b, Vt);
    dwconv<1,56,56,true ,0><<<dim3(4704), dim3(256), 0, stream>>>(preQ, wtab + 0*9*NC, q_dw_b, Qc);
    // 3. attention: 624 = 48 bh x 13 q-tiles of 256
    attn_fwd<<<dim3(624), dim3(512), 0, stream>>>(Qc, Kpk, Vt, ctx);
    // 4. output projection -> f32 d_out
    gemm_bt_bf<true><<<dim3(196*3), dim3(256), 0, stream>>>(
        ctx, wbf + (size_t)3*NC*NC, ball + 3*NC, nullptr, nullptr, nullptr, outf, 3);
}

// Round 11
// 208.479 us; speedup vs baseline: 2.1086x; 2.1086x over previous
//
#include <hip/hip_runtime.h>
#include <hip/hip_bf16.h>
#include <stdint.h>

typedef __attribute__((ext_vector_type(4))) float f32x4;
typedef __attribute__((ext_vector_type(8))) short s16x8;
typedef __attribute__((ext_vector_type(4))) short s16x4;
typedef __attribute__((ext_vector_type(8))) unsigned short u16x8;

#define NB 8
#define HH 56
#define WW0 56
#define NC 384
#define NQTOK (HH*WW0)     // 3136
#define NKTOK 784
#define NHEAD 6
#define HDIM 64
// scale folded into q-conv: (1/sqrt(64)) * log2(e)
#define QSCALE 0.18033688f

__device__ __forceinline__ float bf2f(unsigned short u) {
    union { unsigned int i; float f; } x; x.i = ((unsigned int)u) << 16; return x.f;
}
__device__ __forceinline__ unsigned short f2bf(float f) {
    union { float f; unsigned int i; } x; x.f = f;
    unsigned int r = x.i + 0x7FFFu + ((x.i >> 16) & 1u);
    return (unsigned short)(r >> 16);
}

// ---------- prep kernels ----------
__global__ __launch_bounds__(256) void cvt_bf16(const float* __restrict__ src,
                                                unsigned short* __restrict__ dst, int n8) {
    int i = blockIdx.x*256 + threadIdx.x;
    if (i >= n8) return;
    f32x4 a0 = *(const f32x4*)&src[(size_t)i*8];
    f32x4 a1 = *(const f32x4*)&src[(size_t)i*8 + 4];
    u16x8 p;
    #pragma unroll
    for (int j = 0; j < 4; ++j) { p[j] = f2bf(a0[j]); p[j+4] = f2bf(a1[j]); }
    *(u16x8*)&dst[(size_t)i*8] = p;
}

__global__ __launch_bounds__(256) void cvt_w4(
    const float* __restrict__ a, const float* __restrict__ b,
    const float* __restrict__ c, const float* __restrict__ d,
    unsigned short* __restrict__ dst) {
    int i = blockIdx.x*256 + threadIdx.x;              // 73728 = 4*147456/8
    if (i >= 73728) return;
    int m = i / 18432;
    const float* s = (m==0) ? a : ((m==1) ? b : ((m==2) ? c : d));
    int r = i - m*18432;
    f32x4 a0 = *(const f32x4*)&s[(size_t)r*8];
    f32x4 a1 = *(const f32x4*)&s[(size_t)r*8 + 4];
    u16x8 p;
    #pragma unroll
    for (int j = 0; j < 4; ++j) { p[j] = f2bf(a0[j]); p[j+4] = f2bf(a1[j]); }
    *(u16x8*)&dst[(size_t)i*8] = p;
}

__global__ __launch_bounds__(256) void cvt_bias(
    const float* __restrict__ a, const float* __restrict__ b,
    const float* __restrict__ c, const float* __restrict__ d,
    float* __restrict__ dst) {
    int i = blockIdx.x*256 + threadIdx.x;
    if (i >= 4*NC) return;
    int m = i / NC, r = i - m*NC;
    dst[i] = ((m==0) ? a : ((m==1) ? b : ((m==2) ? c : d)))[r];
}

__global__ __launch_bounds__(256) void prep_w(
    const float* __restrict__ qw, const float* __restrict__ kw, const float* __restrict__ vw,
    float* __restrict__ wt)   // [3][9][NC]
{
    int i = blockIdx.x*256 + threadIdx.x;
    if (i >= 3*9*NC) return;
    int m = i / (9*NC); int r = i - m*(9*NC);
    int tap = r / NC; int c = r - tap*NC;
    const float* src = (m==0) ? qw : ((m==1) ? kw : vw);
    wt[i] = src[c*9 + tap];
}

// ---------- GEMM (pure bf16 operands, XOR-swizzled LDS) — round-7-proven ----------
template<bool OUT_F32>
__global__ __launch_bounds__(256) void gemm_bt_bf(
    const unsigned short* __restrict__ A,
    const unsigned short* __restrict__ Wall,  // [nmat][384*384] bf16
    const float* __restrict__ Ball,           // [nmat][384] f32
    unsigned short* __restrict__ Oa, unsigned short* __restrict__ Ob, unsigned short* __restrict__ Oc,
    float* __restrict__ Of,
    int ntiles)
{
    __shared__ unsigned short lA[128*64];
    __shared__ unsigned short lW[128*64];
    char* lAb = (char*)lA;
    char* lWb = (char*)lW;
    const int bid = blockIdx.x;
    const int nt = bid % ntiles;
    const int mt = bid / ntiles;
    const int mat = nt / 3;
    const int ncol = nt - mat*3;
    const unsigned short* W = Wall + (size_t)mat*NC*NC;
    const float* Bsel = Ball + mat*NC;
    unsigned short* Osel = (mat==0) ? Oa : ((mat==1) ? Ob : Oc);
    const int Mbase = mt*128, Nbase = ncol*128;
    const int t = threadIdx.x;
    const int w = t >> 6, l = t & 63;
    const int wr = w >> 1, wc = w & 1;
    const int lr = l & 15, lg = l >> 4;
    const int swg = (lr & 7) << 4;

    f32x4 acc[4][4] = {};
    for (int kt = 0; kt < 6; ++kt) {
        __syncthreads();
        #pragma unroll
        for (int i = 0; i < 4; ++i) {
            int c = i*256 + t;
            int row = c >> 3, c8 = c & 7;
            int sdst = row*128 + ((c8*16) ^ ((row & 7) << 4));
            *(u16x8*)(lAb + sdst) = *(const u16x8*)&A[(size_t)(Mbase+row)*NC + kt*64 + c8*8];
            *(u16x8*)(lWb + sdst) = *(const u16x8*)&W[(size_t)(Nbase+row)*NC + kt*64 + c8*8];
        }
        __syncthreads();
        #pragma unroll
        for (int kk = 0; kk < 2; ++kk) {
            s16x8 af[4], bfr[4];
            #pragma unroll
            for (int m = 0; m < 4; ++m)
                af[m] = *(const s16x8*)(lAb + (wr*64 + m*16 + lr)*128 + ((kk*64 + lg*16) ^ swg));
            #pragma unroll
            for (int n = 0; n < 4; ++n)
                bfr[n] = *(const s16x8*)(lWb + (wc*64 + n*16 + lr)*128 + ((kk*64 + lg*16) ^ swg));
            #pragma unroll
            for (int m = 0; m < 4; ++m)
                #pragma unroll
                for (int n = 0; n < 4; ++n)
                    acc[m][n] = __builtin_amdgcn_mfma_f32_16x16x32_bf16(af[m], bfr[n], acc[m][n], 0, 0, 0);
        }
    }
    #pragma unroll
    for (int n = 0; n < 4; ++n) {
        int col = Nbase + wc*64 + n*16 + lr;
        float bias = Bsel[col];
        #pragma unroll
        for (int m = 0; m < 4; ++m) {
            int row0 = Mbase + wr*64 + m*16 + lg*4;
            #pragma unroll
            for (int r = 0; r < 4; ++r) {
                float vv = acc[m][n][r] + bias;
                if (OUT_F32) Of[(size_t)(row0 + r)*NC + col] = vv;
                else Osel[(size_t)(row0 + r)*NC + col] = f2bf(vv);
            }
        }
    }
}

// ---------- depthwise conv ----------
// MODE: 0 = token layout (b,tok,384); 1 = head-packed K (bh,tok,64); 2 = transposed V (bh,d,tok)
template<int S, int HO, int WO, bool SCALE, int MODE>
__global__ __launch_bounds__(256) void dwconv(
    const unsigned short* __restrict__ in,
    const float* __restrict__ wt9,   // (9, NC) transposed
    const float* __restrict__ bias,  // (NC)
    unsigned short* __restrict__ outp)
{
    const int nc8 = NC/8;
    int idx = blockIdx.x*256 + threadIdx.x;
    if (idx >= NB*HO*WO*nc8) return;
    int c8 = idx % nc8; int rest = idx / nc8;
    int wo = rest % WO; rest /= WO;
    int ho = rest % HO; int b = rest / HO;
    int c0 = c8*8;
    f32x4 b0 = *(const f32x4*)&bias[c0];
    f32x4 b1 = *(const f32x4*)&bias[c0+4];
    float acc[8];
    #pragma unroll
    for (int j = 0; j < 4; ++j) { acc[j] = b0[j]; acc[j+4] = b1[j]; }
    #pragma unroll
    for (int kh = 0; kh < 3; ++kh) {
        int h = ho*S + kh - 1;
        if (h < 0 || h >= HH) continue;
        #pragma unroll
        for (int kw = 0; kw < 3; ++kw) {
            int ww = wo*S + kw - 1;
            if (ww < 0 || ww >= WW0) continue;
            int tap = kh*3 + kw;
            u16x8 xv = *(const u16x8*)&in[((size_t)b*(HH*WW0) + h*WW0 + ww)*NC + c0];
            f32x4 w0 = *(const f32x4*)&wt9[tap*NC + c0];
            f32x4 w1 = *(const f32x4*)&wt9[tap*NC + c0 + 4];
            #pragma unroll
            for (int j = 0; j < 4; ++j) {
                acc[j]   += bf2f(xv[j])   * w0[j];
                acc[j+4] += bf2f(xv[j+4]) * w1[j];
            }
        }
    }
    if (SCALE) {
        #pragma unroll
        for (int j = 0; j < 8; ++j) acc[j] *= QSCALE;
    }
    int tok = ho*WO + wo;
    int hh = c0 >> 6, d0 = c0 & 63;
    if (MODE == 0) {
        u16x8 ov;
        #pragma unroll
        for (int j = 0; j < 8; ++j) ov[j] = f2bf(acc[j]);
        *(u16x8*)&outp[((size_t)b*(HO*WO) + tok)*NC + c0] = ov;
    } else if (MODE == 1) {
        u16x8 ov;
        #pragma unroll
        for (int j = 0; j < 8; ++j) ov[j] = f2bf(acc[j]);
        *(u16x8*)&outp[((size_t)(b*NHEAD + hh)*(HO*WO) + tok)*HDIM + d0] = ov;
    } else {
        size_t base = ((size_t)(b*NHEAD + hh)*HDIM + d0)*(HO*WO) + tok;
        #pragma unroll
        for (int j = 0; j < 8; ++j)
            outp[base + (size_t)j*(HO*WO)] = f2bf(acc[j]);
    }
}

// ---------- attention (round-5 submission, byte-proven at 98 us) ----------
// sign(s)*softmax(|s|), no max tracking, per-lane deferred denominator.
// 4 waves/block, 128 q rows/block, KVBLK=64; LDS-staged double-buffered K/V,
// reg-staged issue-early/write-late; XOR swizzle byte^=((row&7)<<4).
__global__ __launch_bounds__(256) void attn_fwd(
    const unsigned short* __restrict__ Q,   // (NB, 3136, 384) bf16 pre-scaled by 0.125*log2e
    const unsigned short* __restrict__ Kpk, // (48, 784, 64) bf16 head-packed
    const unsigned short* __restrict__ Vt,  // (48, 64, 784) bf16 transposed
    unsigned short* __restrict__ ctx)       // (NB, 3136, 384) bf16
{
    __shared__ unsigned short lK[2][4096];
    __shared__ unsigned short lV[2][4096];
    const int bid = blockIdx.x;             // 1200 = 8 XCD * 6 bh * 25 qt
    const int xcd = bid & 7, slot = bid >> 3;
    const int bh = xcd*6 + slot/25;
    const int qt = slot % 25;
    const int b = bh / NHEAD, h = bh - b*NHEAD;
    const int t = threadIdx.x;
    const int w = t >> 6, l = t & 63;
    const int lq = l & 15, lg = l >> 4;
    const int wq0 = qt*128 + w*32;
    const int wq0c = (wq0 > NQTOK-32) ? (NQTOK-32) : wq0;   // clamp: all waves run barriers

    const unsigned short* Qb = Q + ((size_t)b*NQTOK + wq0c + lq)*NC + h*HDIM;
    s16x8 qA[2][2];
    qA[0][0] = *(const s16x8*)&Qb[lg*8];
    qA[0][1] = *(const s16x8*)&Qb[32 + lg*8];
    qA[1][0] = *(const s16x8*)&Qb[16*NC + lg*8];
    qA[1][1] = *(const s16x8*)&Qb[16*NC + 32 + lg*8];

    const char* Kg = (const char*)(Kpk + (size_t)bh*NKTOK*HDIM);
    const char* Vg = (const char*)(Vt + (size_t)bh*HDIM*NKTOK);
    char* lKb = (char*)lK;
    char* lVb = (char*)lV;

    // staging: 512 x 16B chunks per 8KB tile; two K-chunks + two V-chunks per thread
    const int cr0 = t >> 3;           // rows 0..31
    const int cr1 = cr0 + 32;         // rows 32..63
    const int cc  = (t & 7) * 16;     // byte col in 128B row
    const int dst0 = cr0*128 + (cc ^ ((cr0 & 7) << 4));
    const int dst1 = cr1*128 + (cc ^ ((cr1 & 7) << 4));

    uint4 rk0, rk1, rv0, rv1;
    #define LOADT(kb) do { \
        rk0 = *(const uint4*)(Kg + (size_t)((kb) + cr0)*128 + cc); \
        rk1 = *(const uint4*)(Kg + (size_t)((kb) + cr1)*128 + cc); \
        rv0 = *(const uint4*)(Vg + (size_t)cr0*1568 + (kb)*2 + cc); \
        rv1 = *(const uint4*)(Vg + (size_t)cr1*1568 + (kb)*2 + cc); \
    } while(0)
    #define WRITET(buf) do { \
        *(uint4*)(lKb + (buf)*8192 + dst0) = rk0; \
        *(uint4*)(lKb + (buf)*8192 + dst1) = rk1; \
        *(uint4*)(lVb + (buf)*8192 + dst0) = rv0; \
        *(uint4*)(lVb + (buf)*8192 + dst1) = rv1; \
    } while(0)

    const int swc = (lq & 7) << 4;
    const int ck0 = (lg*16) ^ swc;          // K frag half 0, byte col
    const int ck1 = (64 + lg*16) ^ swc;     // K frag half 1

    float ls[2] = {0.f, 0.f};
    f32x4 oacc[2][4] = {};

    LOADT(0);
    WRITET(0);
    __syncthreads();

    for (int kt = 0; kt < 12; ++kt) {
        const int cur = kt & 1;
        if (kt < 11) LOADT((kt+1)*64);
        const char* Kl = lKb + cur*8192;
        const char* Vl = lVb + cur*8192;
        f32x4 st[2][4] = {};
        __builtin_amdgcn_s_setprio(1);
        #pragma unroll
        for (int kfr = 0; kfr < 4; ++kfr) {
            int rb = (kfr*16 + lq)*128;
            s16x8 kf0 = *(const s16x8*)(Kl + rb + ck0);
            s16x8 kf1 = *(const s16x8*)(Kl + rb + ck1);
            st[0][kfr] = __builtin_amdgcn_mfma_f32_16x16x32_bf16(kf0, qA[0][0], st[0][kfr], 0,0,0);
            st[0][kfr] = __builtin_amdgcn_mfma_f32_16x16x32_bf16(kf1, qA[0][1], st[0][kfr], 0,0,0);
            st[1][kfr] = __builtin_amdgcn_mfma_f32_16x16x32_bf16(kf0, qA[1][0], st[1][kfr], 0,0,0);
            st[1][kfr] = __builtin_amdgcn_mfma_f32_16x16x32_bf16(kf1, qA[1][1], st[1][kfr], 0,0,0);
        }
        __builtin_amdgcn_s_setprio(0);
        s16x4 pbv[2][4];
        #pragma unroll
        for (int qf = 0; qf < 2; ++qf) {
            float rs = 0.f;
            #pragma unroll
            for (int kfr = 0; kfr < 4; ++kfr)
                #pragma unroll
                for (int r = 0; r < 4; ++r) {
                    float s = st[qf][kfr][r];
                    float e = exp2f(fabsf(s));
                    rs += e;
                    pbv[qf][kfr][r] = (short)f2bf(copysignf(e, s));
                }
            ls[qf] += rs;
        }
        __builtin_amdgcn_s_setprio(1);
        #pragma unroll
        for (int ks = 0; ks < 4; ++ks)
            #pragma unroll
            for (int f = 0; f < 4; ++f) {
                int va = (f*16 + lq)*128 + ((ks*32 + lg*8) ^ swc);
                s16x4 vvf = *(const s16x4*)(Vl + va);
                oacc[0][f] = __builtin_amdgcn_mfma_f32_16x16x16bf16_1k(vvf, pbv[0][ks], oacc[0][f], 0,0,0);
                oacc[1][f] = __builtin_amdgcn_mfma_f32_16x16x16bf16_1k(vvf, pbv[1][ks], oacc[1][f], 0,0,0);
            }
        __builtin_amdgcn_s_setprio(0);
        if (kt < 11) {
            WRITET(cur ^ 1);
            __syncthreads();
        }
    }
    // tail: k = 768..783 direct from global
    {
        const unsigned short* Kb2 = (const unsigned short*)Kg;
        const unsigned short* Vb2 = (const unsigned short*)Vg;
        const unsigned short* kr = &Kb2[(size_t)(768 + lq)*HDIM];
        s16x8 kf0 = *(const s16x8*)&kr[lg*8];
        s16x8 kf1 = *(const s16x8*)&kr[32 + lg*8];
        f32x4 st[2] = {};
        st[0] = __builtin_amdgcn_mfma_f32_16x16x32_bf16(kf0, qA[0][0], st[0], 0,0,0);
        st[0] = __builtin_amdgcn_mfma_f32_16x16x32_bf16(kf1, qA[0][1], st[0], 0,0,0);
        st[1] = __builtin_amdgcn_mfma_f32_16x16x32_bf16(kf0, qA[1][0], st[1], 0,0,0);
        st[1] = __builtin_amdgcn_mfma_f32_16x16x32_bf16(kf1, qA[1][1], st[1], 0,0,0);
        s16x4 vv[4];
        #pragma unroll
        for (int f = 0; f < 4; ++f)
            vv[f] = *(const s16x4*)&Vb2[(size_t)(f*16 + lq)*NKTOK + 768 + lg*4];
        s16x4 pbv[2];
        #pragma unroll
        for (int qf = 0; qf < 2; ++qf) {
            float rs = 0.f;
            #pragma unroll
            for (int r = 0; r < 4; ++r) {
                float s = st[qf][r];
                float e = exp2f(fabsf(s));
                rs += e;
                pbv[qf][r] = (short)f2bf(copysignf(e, s));
            }
            ls[qf] += rs;
        }
        #pragma unroll
        for (int f = 0; f < 4; ++f) {
            oacc[0][f] = __builtin_amdgcn_mfma_f32_16x16x16bf16_1k(vv[f], pbv[0], oacc[0][f], 0,0,0);
            oacc[1][f] = __builtin_amdgcn_mfma_f32_16x16x16bf16_1k(vv[f], pbv[1], oacc[1][f], 0,0,0);
        }
    }
    if (wq0 < NQTOK) {
        #pragma unroll
        for (int qf = 0; qf < 2; ++qf) {
            float lr2 = ls[qf];
            lr2 += __shfl_xor(lr2, 16);
            lr2 += __shfl_xor(lr2, 32);
            float inv = 1.f / lr2;
            unsigned short* cb = ctx + ((size_t)b*NQTOK + wq0 + qf*16 + lq)*NC + h*HDIM;
            #pragma unroll
            for (int f = 0; f < 4; ++f) {
                s16x4 o;
                #pragma unroll
                for (int r = 0; r < 4; ++r) o[r] = (short)f2bf(oacc[qf][f][r] * inv);
                *(s16x4*)&cb[f*16 + lg*4] = o;
            }
        }
    }
    #undef LOADT
    #undef WRITET
}

extern "C" void kernel_launch(void* const* d_in, const int* in_sizes, int n_in,
                              void* d_out, int out_size, void* d_ws, size_t ws_size,
                              hipStream_t stream)
{
    (void)in_sizes; (void)n_in; (void)out_size; (void)ws_size;
    const float* x      = (const float*)d_in[0];
    const float* q_w    = (const float*)d_in[3];
    const float* q_b    = (const float*)d_in[4];
    const float* k_w    = (const float*)d_in[5];
    const float* k_b    = (const float*)d_in[6];
    const float* v_w    = (const float*)d_in[7];
    const float* v_b    = (const float*)d_in[8];
    const float* q_dw_w = (const float*)d_in[9];
    const float* q_dw_b = (const float*)d_in[10];
    const float* k_dw_w = (const float*)d_in[11];
    const float* k_dw_b = (const float*)d_in[12];
    const float* v_dw_w = (const float*)d_in[13];
    const float* v_dw_b = (const float*)d_in[14];
    const float* proj_w = (const float*)d_in[15];
    const float* proj_b = (const float*)d_in[16];
    float* outf = (float*)d_out;
    unsigned short* ws  = (unsigned short*)d_ws;

    const size_t nQ  = (size_t)NB*NQTOK*NC;   // 9,633,792 elems
    const size_t nKc = (size_t)NB*NKTOK*NC;   // 2,408,448 elems
    unsigned short* preQ = ws;                // bf16 pre-conv Q
    unsigned short* preK = ws + nQ;           // bf16 pre-conv K; later ctx
    unsigned short* Kpk  = ws + 2*nQ;         // bf16 post-conv K, head-packed (bh,k,64)
    unsigned short* Vt   = Kpk + nKc;         // bf16 post-conv V, transposed (bh,d,k)
    unsigned short* wbf  = Vt + nKc;          // bf16 [4][384*384] dense weights
    float* wtab = (float*)(wbf + (size_t)4*NC*NC);   // [3][9][384] dw weights transposed
    float* ball = wtab + 3*9*NC;              // [4][384] biases
    unsigned short* preV = (unsigned short*)d_out;          // d_out lower half
    unsigned short* Qc   = (unsigned short*)d_out;          // after preV consumed
    unsigned short* xbf  = ((unsigned short*)d_out) + nQ;   // d_out upper half: bf16 x
    unsigned short* ctx  = preK;              // reuse preK after k-conv

    // 0. prep: dtype conversions + weight transposes
    cvt_bf16<<<dim3(4704), dim3(256), 0, stream>>>(x, xbf, (int)(nQ/8));
    cvt_w4  <<<dim3(288),  dim3(256), 0, stream>>>(q_w, k_w, v_w, proj_w, wbf);
    cvt_bias<<<dim3(6),    dim3(256), 0, stream>>>(q_b, k_b, v_b, proj_b, ball);
    prep_w  <<<dim3(41),   dim3(256), 0, stream>>>(q_dw_w, k_dw_w, v_dw_w, wtab);
    // 1. QKV projections (bf16 x bf16): Q->preQ, K->preK, V->preV(d_out)
    gemm_bt_bf<false><<<dim3(196*9), dim3(256), 0, stream>>>(
        xbf, wbf, ball, preQ, preK, preV, nullptr, 9);
    // 2. depthwise convs; K head-packed, V transposed, Q scaled by 0.125*log2e
    dwconv<2,28,28,false,1><<<dim3(1176), dim3(256), 0, stream>>>(preK, wtab + 1*9*NC, k_dw_b, Kpk);
    dwconv<2,28,28,false,2><<<dim3(1176), dim3(256), 0, stream>>>(preV, wtab + 2*9*NC, v_dw_b, Vt);
    dwconv<1,56,56,true ,0><<<dim3(4704), dim3(256), 0, stream>>>(preQ, wtab + 0*9*NC, q_dw_b, Qc);
    // 3. attention: 1200 = 48 bh x 25 q-tiles of 128
    attn_fwd<<<dim3(1200), dim3(256), 0, stream>>>(Qc, Kpk, Vt, ctx);
    // 4. output projection -> f32 d_out
    gemm_bt_bf<true><<<dim3(196*3), dim3(256), 0, stream>>>(
        ctx, wbf + (size_t)3*NC*NC, ball + 3*NC, nullptr, nullptr, nullptr, outf, 3);
}

// Round 12
// 196.098 us; speedup vs baseline: 2.2417x; 1.0631x over previous
//
#include <hip/hip_runtime.h>
#include <hip/hip_bf16.h>
#include <stdint.h>

typedef __attribute__((ext_vector_type(4))) float f32x4;
typedef __attribute__((ext_vector_type(8))) short s16x8;
typedef __attribute__((ext_vector_type(4))) short s16x4;
typedef __attribute__((ext_vector_type(8))) unsigned short u16x8;

#define NB 8
#define HH 56
#define WW0 56
#define NC 384
#define NQTOK (HH*WW0)     // 3136
#define NKTOK 784
#define NHEAD 6
#define HDIM 64
// scale folded into q-conv: (1/sqrt(64)) * log2(e)
#define QSCALE 0.18033688f

__device__ __forceinline__ float bf2f(unsigned short u) {
    union { unsigned int i; float f; } x; x.i = ((unsigned int)u) << 16; return x.f;
}
__device__ __forceinline__ unsigned short f2bf(float f) {
    union { float f; unsigned int i; } x; x.f = f;
    unsigned int r = x.i + 0x7FFFu + ((x.i >> 16) & 1u);
    return (unsigned short)(r >> 16);
}
// round-half-up bf16: 2 ops vs RNE's 5; differs only on exact ties (P-packing only)
__device__ __forceinline__ unsigned short f2bf_rn(float f) {
    union { float f; unsigned int i; } x; x.f = f;
    return (unsigned short)((x.i + 0x8000u) >> 16);
}

// ---------- prep kernels ----------
__global__ __launch_bounds__(256) void cvt_bf16(const float* __restrict__ src,
                                                unsigned short* __restrict__ dst, int n8) {
    int i = blockIdx.x*256 + threadIdx.x;
    if (i >= n8) return;
    f32x4 a0 = *(const f32x4*)&src[(size_t)i*8];
    f32x4 a1 = *(const f32x4*)&src[(size_t)i*8 + 4];
    u16x8 p;
    #pragma unroll
    for (int j = 0; j < 4; ++j) { p[j] = f2bf(a0[j]); p[j+4] = f2bf(a1[j]); }
    *(u16x8*)&dst[(size_t)i*8] = p;
}

__global__ __launch_bounds__(256) void cvt_w4(
    const float* __restrict__ a, const float* __restrict__ b,
    const float* __restrict__ c, const float* __restrict__ d,
    unsigned short* __restrict__ dst) {
    int i = blockIdx.x*256 + threadIdx.x;              // 73728 = 4*147456/8
    if (i >= 73728) return;
    int m = i / 18432;
    const float* s = (m==0) ? a : ((m==1) ? b : ((m==2) ? c : d));
    int r = i - m*18432;
    f32x4 a0 = *(const f32x4*)&s[(size_t)r*8];
    f32x4 a1 = *(const f32x4*)&s[(size_t)r*8 + 4];
    u16x8 p;
    #pragma unroll
    for (int j = 0; j < 4; ++j) { p[j] = f2bf(a0[j]); p[j+4] = f2bf(a1[j]); }
    *(u16x8*)&dst[(size_t)i*8] = p;
}

__global__ __launch_bounds__(256) void cvt_bias(
    const float* __restrict__ a, const float* __restrict__ b,
    const float* __restrict__ c, const float* __restrict__ d,
    float* __restrict__ dst) {
    int i = blockIdx.x*256 + threadIdx.x;
    if (i >= 4*NC) return;
    int m = i / NC, r = i - m*NC;
    dst[i] = ((m==0) ? a : ((m==1) ? b : ((m==2) ? c : d)))[r];
}

__global__ __launch_bounds__(256) void prep_w(
    const float* __restrict__ qw, const float* __restrict__ kw, const float* __restrict__ vw,
    float* __restrict__ wt)   // [3][9][NC]
{
    int i = blockIdx.x*256 + threadIdx.x;
    if (i >= 3*9*NC) return;
    int m = i / (9*NC); int r = i - m*(9*NC);
    int tap = r / NC; int c = r - tap*NC;
    const float* src = (m==0) ? qw : ((m==1) ? kw : vw);
    wt[i] = src[c*9 + tap];
}

// ---------- GEMM: 256x128 tile, BK=64, 8 waves (4x2), XOR-swizzled LDS ----------
template<bool OUT_F32>
__global__ __launch_bounds__(512) void gemm_bt_bf(
    const unsigned short* __restrict__ A,
    const unsigned short* __restrict__ Wall,  // [nmat][384*384] bf16
    const float* __restrict__ Ball,           // [nmat][384] f32
    unsigned short* __restrict__ Oa, unsigned short* __restrict__ Ob, unsigned short* __restrict__ Oc,
    float* __restrict__ Of,
    int ntiles)
{
    __shared__ unsigned short lA[256*64];   // 32 KB
    __shared__ unsigned short lW[128*64];   // 16 KB
    char* lAb = (char*)lA;
    char* lWb = (char*)lW;
    const int bid = blockIdx.x;
    const int nt = bid % ntiles;      // nt-major: A-tile reuse temporally local
    const int mt = bid / ntiles;
    const int mat = nt / 3;
    const int ncol = nt - mat*3;
    const unsigned short* W = Wall + (size_t)mat*NC*NC;
    const float* Bsel = Ball + mat*NC;
    unsigned short* Osel = (mat==0) ? Oa : ((mat==1) ? Ob : Oc);
    const int Mbase = mt*256, Nbase = ncol*128;
    const int t = threadIdx.x;
    const int w = t >> 6, l = t & 63;
    const int wr = w >> 1, wc = w & 1;       // wr 0..3, wc 0..1
    const int lr = l & 15, lg = l >> 4;
    const int swg = (lr & 7) << 4;

    f32x4 acc[4][4] = {};
    for (int kt = 0; kt < 6; ++kt) {
        __syncthreads();
        #pragma unroll
        for (int i = 0; i < 4; ++i) {        // A: 2048 chunks of 16B
            int c = i*512 + t;
            int row = c >> 3, c8 = c & 7;
            int sdst = row*128 + ((c8*16) ^ ((row & 7) << 4));
            *(u16x8*)(lAb + sdst) = *(const u16x8*)&A[(size_t)(Mbase+row)*NC + kt*64 + c8*8];
        }
        #pragma unroll
        for (int i = 0; i < 2; ++i) {        // W: 1024 chunks
            int c = i*512 + t;
            int row = c >> 3, c8 = c & 7;
            int sdst = row*128 + ((c8*16) ^ ((row & 7) << 4));
            *(u16x8*)(lWb + sdst) = *(const u16x8*)&W[(size_t)(Nbase+row)*NC + kt*64 + c8*8];
        }
        __syncthreads();
        #pragma unroll
        for (int kk = 0; kk < 2; ++kk) {
            s16x8 af[4], bfr[4];
            #pragma unroll
            for (int m = 0; m < 4; ++m)
                af[m] = *(const s16x8*)(lAb + (wr*64 + m*16 + lr)*128 + ((kk*64 + lg*16) ^ swg));
            #pragma unroll
            for (int n = 0; n < 4; ++n)
                bfr[n] = *(const s16x8*)(lWb + (wc*64 + n*16 + lr)*128 + ((kk*64 + lg*16) ^ swg));
            #pragma unroll
            for (int m = 0; m < 4; ++m)
                #pragma unroll
                for (int n = 0; n < 4; ++n)
                    acc[m][n] = __builtin_amdgcn_mfma_f32_16x16x32_bf16(af[m], bfr[n], acc[m][n], 0, 0, 0);
        }
    }
    #pragma unroll
    for (int n = 0; n < 4; ++n) {
        int col = Nbase + wc*64 + n*16 + lr;
        float bias = Bsel[col];
        #pragma unroll
        for (int m = 0; m < 4; ++m) {
            int row0 = Mbase + wr*64 + m*16 + lg*4;
            #pragma unroll
            for (int r = 0; r < 4; ++r) {
                float vv = acc[m][n][r] + bias;
                if (OUT_F32) Of[(size_t)(row0 + r)*NC + col] = vv;
                else Osel[(size_t)(row0 + r)*NC + col] = f2bf(vv);
            }
        }
    }
}

// ---------- depthwise conv ----------
// MODE: 0 = token layout (b,tok,384); 1 = head-packed K (bh,tok,64); 2 = transposed V (bh,d,tok)
template<int S, int HO, int WO, bool SCALE, int MODE>
__global__ __launch_bounds__(256) void dwconv(
    const unsigned short* __restrict__ in,
    const float* __restrict__ wt9,   // (9, NC) transposed
    const float* __restrict__ bias,  // (NC)
    unsigned short* __restrict__ outp)
{
    const int nc8 = NC/8;
    int idx = blockIdx.x*256 + threadIdx.x;
    if (idx >= NB*HO*WO*nc8) return;
    int c8 = idx % nc8; int rest = idx / nc8;
    int wo = rest % WO; rest /= WO;
    int ho = rest % HO; int b = rest / HO;
    int c0 = c8*8;
    f32x4 b0 = *(const f32x4*)&bias[c0];
    f32x4 b1 = *(const f32x4*)&bias[c0+4];
    float acc[8];
    #pragma unroll
    for (int j = 0; j < 4; ++j) { acc[j] = b0[j]; acc[j+4] = b1[j]; }
    #pragma unroll
    for (int kh = 0; kh < 3; ++kh) {
        int h = ho*S + kh - 1;
        if (h < 0 || h >= HH) continue;
        #pragma unroll
        for (int kw = 0; kw < 3; ++kw) {
            int ww = wo*S + kw - 1;
            if (ww < 0 || ww >= WW0) continue;
            int tap = kh*3 + kw;
            u16x8 xv = *(const u16x8*)&in[((size_t)b*(HH*WW0) + h*WW0 + ww)*NC + c0];
            f32x4 w0 = *(const f32x4*)&wt9[tap*NC + c0];
            f32x4 w1 = *(const f32x4*)&wt9[tap*NC + c0 + 4];
            #pragma unroll
            for (int j = 0; j < 4; ++j) {
                acc[j]   += bf2f(xv[j])   * w0[j];
                acc[j+4] += bf2f(xv[j+4]) * w1[j];
            }
        }
    }
    if (SCALE) {
        #pragma unroll
        for (int j = 0; j < 8; ++j) acc[j] *= QSCALE;
    }
    int tok = ho*WO + wo;
    int hh = c0 >> 6, d0 = c0 & 63;
    if (MODE == 0) {
        u16x8 ov;
        #pragma unroll
        for (int j = 0; j < 8; ++j) ov[j] = f2bf(acc[j]);
        *(u16x8*)&outp[((size_t)b*(HO*WO) + tok)*NC + c0] = ov;
    } else if (MODE == 1) {
        u16x8 ov;
        #pragma unroll
        for (int j = 0; j < 8; ++j) ov[j] = f2bf(acc[j]);
        *(u16x8*)&outp[((size_t)(b*NHEAD + hh)*(HO*WO) + tok)*HDIM + d0] = ov;
    } else {
        size_t base = ((size_t)(b*NHEAD + hh)*HDIM + d0)*(HO*WO) + tok;
        #pragma unroll
        for (int j = 0; j < 8; ++j)
            outp[base + (size_t)j*(HO*WO)] = f2bf(acc[j]);
    }
}

// ---------- attention (proven 98us structure; P-packing uses 2-op round) ----------
// sign(s)*softmax(|s|), no max tracking, per-lane deferred denominator.
// 4 waves/block, 128 q rows/block, KVBLK=64; LDS-staged double-buffered K/V,
// reg-staged issue-early/write-late; XOR swizzle byte^=((row&7)<<4).
__global__ __launch_bounds__(256) void attn_fwd(
    const unsigned short* __restrict__ Q,   // (NB, 3136, 384) bf16 pre-scaled by 0.125*log2e
    const unsigned short* __restrict__ Kpk, // (48, 784, 64) bf16 head-packed
    const unsigned short* __restrict__ Vt,  // (48, 64, 784) bf16 transposed
    unsigned short* __restrict__ ctx)       // (NB, 3136, 384) bf16
{
    __shared__ unsigned short lK[2][4096];
    __shared__ unsigned short lV[2][4096];
    const int bid = blockIdx.x;             // 1200 = 8 XCD * 6 bh * 25 qt
    const int xcd = bid & 7, slot = bid >> 3;
    const int bh = xcd*6 + slot/25;
    const int qt = slot % 25;
    const int b = bh / NHEAD, h = bh - b*NHEAD;
    const int t = threadIdx.x;
    const int w = t >> 6, l = t & 63;
    const int lq = l & 15, lg = l >> 4;
    const int wq0 = qt*128 + w*32;
    const int wq0c = (wq0 > NQTOK-32) ? (NQTOK-32) : wq0;   // clamp: all waves run barriers

    const unsigned short* Qb = Q + ((size_t)b*NQTOK + wq0c + lq)*NC + h*HDIM;
    s16x8 qA[2][2];
    qA[0][0] = *(const s16x8*)&Qb[lg*8];
    qA[0][1] = *(const s16x8*)&Qb[32 + lg*8];
    qA[1][0] = *(const s16x8*)&Qb[16*NC + lg*8];
    qA[1][1] = *(const s16x8*)&Qb[16*NC + 32 + lg*8];

    const char* Kg = (const char*)(Kpk + (size_t)bh*NKTOK*HDIM);
    const char* Vg = (const char*)(Vt + (size_t)bh*HDIM*NKTOK);
    char* lKb = (char*)lK;
    char* lVb = (char*)lV;

    // staging: 512 x 16B chunks per 8KB tile; two K-chunks + two V-chunks per thread
    const int cr0 = t >> 3;           // rows 0..31
    const int cr1 = cr0 + 32;         // rows 32..63
    const int cc  = (t & 7) * 16;     // byte col in 128B row
    const int dst0 = cr0*128 + (cc ^ ((cr0 & 7) << 4));
    const int dst1 = cr1*128 + (cc ^ ((cr1 & 7) << 4));

    uint4 rk0, rk1, rv0, rv1;
    #define LOADT(kb) do { \
        rk0 = *(const uint4*)(Kg + (size_t)((kb) + cr0)*128 + cc); \
        rk1 = *(const uint4*)(Kg + (size_t)((kb) + cr1)*128 + cc); \
        rv0 = *(const uint4*)(Vg + (size_t)cr0*1568 + (kb)*2 + cc); \
        rv1 = *(const uint4*)(Vg + (size_t)cr1*1568 + (kb)*2 + cc); \
    } while(0)
    #define WRITET(buf) do { \
        *(uint4*)(lKb + (buf)*8192 + dst0) = rk0; \
        *(uint4*)(lKb + (buf)*8192 + dst1) = rk1; \
        *(uint4*)(lVb + (buf)*8192 + dst0) = rv0; \
        *(uint4*)(lVb + (buf)*8192 + dst1) = rv1; \
    } while(0)

    const int swc = (lq & 7) << 4;
    const int ck0 = (lg*16) ^ swc;          // K frag half 0, byte col
    const int ck1 = (64 + lg*16) ^ swc;     // K frag half 1

    float ls[2] = {0.f, 0.f};
    f32x4 oacc[2][4] = {};

    LOADT(0);
    WRITET(0);
    __syncthreads();

    for (int kt = 0; kt < 12; ++kt) {
        const int cur = kt & 1;
        if (kt < 11) LOADT((kt+1)*64);
        const char* Kl = lKb + cur*8192;
        const char* Vl = lVb + cur*8192;
        f32x4 st[2][4] = {};
        __builtin_amdgcn_s_setprio(1);
        #pragma unroll
        for (int kfr = 0; kfr < 4; ++kfr) {
            int rb = (kfr*16 + lq)*128;
            s16x8 kf0 = *(const s16x8*)(Kl + rb + ck0);
            s16x8 kf1 = *(const s16x8*)(Kl + rb + ck1);
            st[0][kfr] = __builtin_amdgcn_mfma_f32_16x16x32_bf16(kf0, qA[0][0], st[0][kfr], 0,0,0);
            st[0][kfr] = __builtin_amdgcn_mfma_f32_16x16x32_bf16(kf1, qA[0][1], st[0][kfr], 0,0,0);
            st[1][kfr] = __builtin_amdgcn_mfma_f32_16x16x32_bf16(kf0, qA[1][0], st[1][kfr], 0,0,0);
            st[1][kfr] = __builtin_amdgcn_mfma_f32_16x16x32_bf16(kf1, qA[1][1], st[1][kfr], 0,0,0);
        }
        __builtin_amdgcn_s_setprio(0);
        s16x4 pbv[2][4];
        #pragma unroll
        for (int qf = 0; qf < 2; ++qf) {
            float rs = 0.f;
            #pragma unroll
            for (int kfr = 0; kfr < 4; ++kfr)
                #pragma unroll
                for (int r = 0; r < 4; ++r) {
                    float s = st[qf][kfr][r];
                    float e = exp2f(fabsf(s));
                    rs += e;
                    pbv[qf][kfr][r] = (short)f2bf_rn(copysignf(e, s));
                }
            ls[qf] += rs;
        }
        __builtin_amdgcn_s_setprio(1);
        #pragma unroll
        for (int ks = 0; ks < 4; ++ks)
            #pragma unroll
            for (int f = 0; f < 4; ++f) {
                int va = (f*16 + lq)*128 + ((ks*32 + lg*8) ^ swc);
                s16x4 vvf = *(const s16x4*)(Vl + va);
                oacc[0][f] = __builtin_amdgcn_mfma_f32_16x16x16bf16_1k(vvf, pbv[0][ks], oacc[0][f], 0,0,0);
                oacc[1][f] = __builtin_amdgcn_mfma_f32_16x16x16bf16_1k(vvf, pbv[1][ks], oacc[1][f], 0,0,0);
            }
        __builtin_amdgcn_s_setprio(0);
        if (kt < 11) {
            WRITET(cur ^ 1);
            __syncthreads();
        }
    }
    // tail: k = 768..783 direct from global
    {
        const unsigned short* Kb2 = (const unsigned short*)Kg;
        const unsigned short* Vb2 = (const unsigned short*)Vg;
        const unsigned short* kr = &Kb2[(size_t)(768 + lq)*HDIM];
        s16x8 kf0 = *(const s16x8*)&kr[lg*8];
        s16x8 kf1 = *(const s16x8*)&kr[32 + lg*8];
        f32x4 st[2] = {};
        st[0] = __builtin_amdgcn_mfma_f32_16x16x32_bf16(kf0, qA[0][0], st[0], 0,0,0);
        st[0] = __builtin_amdgcn_mfma_f32_16x16x32_bf16(kf1, qA[0][1], st[0], 0,0,0);
        st[1] = __builtin_amdgcn_mfma_f32_16x16x32_bf16(kf0, qA[1][0], st[1], 0,0,0);
        st[1] = __builtin_amdgcn_mfma_f32_16x16x32_bf16(kf1, qA[1][1], st[1], 0,0,0);
        s16x4 vv[4];
        #pragma unroll
        for (int f = 0; f < 4; ++f)
            vv[f] = *(const s16x4*)&Vb2[(size_t)(f*16 + lq)*NKTOK + 768 + lg*4];
        s16x4 pbv[2];
        #pragma unroll
        for (int qf = 0; qf < 2; ++qf) {
            float rs = 0.f;
            #pragma unroll
            for (int r = 0; r < 4; ++r) {
                float s = st[qf][r];
                float e = exp2f(fabsf(s));
                rs += e;
                pbv[qf][r] = (short)f2bf_rn(copysignf(e, s));
            }
            ls[qf] += rs;
        }
        #pragma unroll
        for (int f = 0; f < 4; ++f) {
            oacc[0][f] = __builtin_amdgcn_mfma_f32_16x16x16bf16_1k(vv[f], pbv[0], oacc[0][f], 0,0,0);
            oacc[1][f] = __builtin_amdgcn_mfma_f32_16x16x16bf16_1k(vv[f], pbv[1], oacc[1][f], 0,0,0);
        }
    }
    if (wq0 < NQTOK) {
        #pragma unroll
        for (int qf = 0; qf < 2; ++qf) {
            float lr2 = ls[qf];
            lr2 += __shfl_xor(lr2, 16);
            lr2 += __shfl_xor(lr2, 32);
            float inv = 1.f / lr2;
            unsigned short* cb = ctx + ((size_t)b*NQTOK + wq0 + qf*16 + lq)*NC + h*HDIM;
            #pragma unroll
            for (int f = 0; f < 4; ++f) {
                s16x4 o;
                #pragma unroll
                for (int r = 0; r < 4; ++r) o[r] = (short)f2bf(oacc[qf][f][r] * inv);
                *(s16x4*)&cb[f*16 + lg*4] = o;
            }
        }
    }
    #undef LOADT
    #undef WRITET
}

extern "C" void kernel_launch(void* const* d_in, const int* in_sizes, int n_in,
                              void* d_out, int out_size, void* d_ws, size_t ws_size,
                              hipStream_t stream)
{
    (void)in_sizes; (void)n_in; (void)out_size; (void)ws_size;
    const float* x      = (const float*)d_in[0];
    const float* q_w    = (const float*)d_in[3];
    const float* q_b    = (const float*)d_in[4];
    const float* k_w    = (const float*)d_in[5];
    const float* k_b    = (const float*)d_in[6];
    const float* v_w    = (const float*)d_in[7];
    const float* v_b    = (const float*)d_in[8];
    const float* q_dw_w = (const float*)d_in[9];
    const float* q_dw_b = (const float*)d_in[10];
    const float* k_dw_w = (const float*)d_in[11];
    const float* k_dw_b = (const float*)d_in[12];
    const float* v_dw_w = (const float*)d_in[13];
    const float* v_dw_b = (const float*)d_in[14];
    const float* proj_w = (const float*)d_in[15];
    const float* proj_b = (const float*)d_in[16];
    float* outf = (float*)d_out;
    unsigned short* ws  = (unsigned short*)d_ws;

    const size_t nQ  = (size_t)NB*NQTOK*NC;   // 9,633,792 elems
    const size_t nKc = (size_t)NB*NKTOK*NC;   // 2,408,448 elems
    unsigned short* preQ = ws;                // bf16 pre-conv Q
    unsigned short* preK = ws + nQ;           // bf16 pre-conv K; later ctx
    unsigned short* Kpk  = ws + 2*nQ;         // bf16 post-conv K, head-packed (bh,k,64)
    unsigned short* Vt   = Kpk + nKc;         // bf16 post-conv V, transposed (bh,d,k)
    unsigned short* wbf  = Vt + nKc;          // bf16 [4][384*384] dense weights
    float* wtab = (float*)(wbf + (size_t)4*NC*NC);   // [3][9][384] dw weights transposed
    float* ball = wtab + 3*9*NC;              // [4][384] biases
    unsigned short* preV = (unsigned short*)d_out;          // d_out lower half
    unsigned short* Qc   = (unsigned short*)d_out;          // after preV consumed
    unsigned short* xbf  = ((unsigned short*)d_out) + nQ;   // d_out upper half: bf16 x
    unsigned short* ctx  = preK;              // reuse preK after k-conv

    // 0. prep: dtype conversions + weight transposes
    cvt_bf16<<<dim3(4704), dim3(256), 0, stream>>>(x, xbf, (int)(nQ/8));
    cvt_w4  <<<dim3(288),  dim3(256), 0, stream>>>(q_w, k_w, v_w, proj_w, wbf);
    cvt_bias<<<dim3(6),    dim3(256), 0, stream>>>(q_b, k_b, v_b, proj_b, ball);
    prep_w  <<<dim3(41),   dim3(256), 0, stream>>>(q_dw_w, k_dw_w, v_dw_w, wtab);
    // 1. QKV projections (bf16 x bf16), 256x128 tiles: Q->preQ, K->preK, V->preV(d_out)
    gemm_bt_bf<false><<<dim3(98*9), dim3(512), 0, stream>>>(
        xbf, wbf, ball, preQ, preK, preV, nullptr, 9);
    // 2. depthwise convs; K head-packed, V transposed, Q scaled by 0.125*log2e
    dwconv<2,28,28,false,1><<<dim3(1176), dim3(256), 0, stream>>>(preK, wtab + 1*9*NC, k_dw_b, Kpk);
    dwconv<2,28,28,false,2><<<dim3(1176), dim3(256), 0, stream>>>(preV, wtab + 2*9*NC, v_dw_b, Vt);
    dwconv<1,56,56,true ,0><<<dim3(4704), dim3(256), 0, stream>>>(preQ, wtab + 0*9*NC, q_dw_b, Qc);
    // 3. attention: 1200 = 48 bh x 25 q-tiles of 128
    attn_fwd<<<dim3(1200), dim3(256), 0, stream>>>(Qc, Kpk, Vt, ctx);
    // 4. output projection (256x128 tiles) -> f32 d_out
    gemm_bt_bf<true><<<dim3(98*3), dim3(512), 0, stream>>>(
        ctx, wbf + (size_t)3*NC*NC, ball + 3*NC, nullptr, nullptr, nullptr, outf, 3);
}

// Round 13
// 182.824 us; speedup vs baseline: 2.4045x; 1.0726x over previous
//
#include <hip/hip_runtime.h>
#include <hip/hip_bf16.h>
#include <stdint.h>

typedef __attribute__((ext_vector_type(4))) float f32x4;
typedef __attribute__((ext_vector_type(8))) short s16x8;
typedef __attribute__((ext_vector_type(4))) short s16x4;
typedef __attribute__((ext_vector_type(8))) unsigned short u16x8;

#define NB 8
#define HH 56
#define WW0 56
#define NC 384
#define NQTOK (HH*WW0)     // 3136
#define NKTOK 784
#define NHEAD 6
#define HDIM 64
// scale folded into q-conv: (1/sqrt(64)) * log2(e)
#define QSCALE 0.18033688f

__device__ __forceinline__ float bf2f(unsigned short u) {
    union { unsigned int i; float f; } x; x.i = ((unsigned int)u) << 16; return x.f;
}
__device__ __forceinline__ unsigned short f2bf(float f) {
    union { float f; unsigned int i; } x; x.f = f;
    unsigned int r = x.i + 0x7FFFu + ((x.i >> 16) & 1u);
    return (unsigned short)(r >> 16);
}
// round-half-up bf16: 2 ops vs RNE's 5; differs only on exact ties (P-packing only)
__device__ __forceinline__ unsigned short f2bf_rn(float f) {
    union { float f; unsigned int i; } x; x.f = f;
    return (unsigned short)((x.i + 0x8000u) >> 16);
}

// ---------- prep kernels ----------
__global__ __launch_bounds__(256) void cvt_bf16(const float* __restrict__ src,
                                                unsigned short* __restrict__ dst, int n8) {
    int i = blockIdx.x*256 + threadIdx.x;
    if (i >= n8) return;
    f32x4 a0 = *(const f32x4*)&src[(size_t)i*8];
    f32x4 a1 = *(const f32x4*)&src[(size_t)i*8 + 4];
    u16x8 p;
    #pragma unroll
    for (int j = 0; j < 4; ++j) { p[j] = f2bf(a0[j]); p[j+4] = f2bf(a1[j]); }
    *(u16x8*)&dst[(size_t)i*8] = p;
}

__global__ __launch_bounds__(256) void cvt_w4(
    const float* __restrict__ a, const float* __restrict__ b,
    const float* __restrict__ c, const float* __restrict__ d,
    unsigned short* __restrict__ dst) {
    int i = blockIdx.x*256 + threadIdx.x;              // 73728 = 4*147456/8
    if (i >= 73728) return;
    int m = i / 18432;
    const float* s = (m==0) ? a : ((m==1) ? b : ((m==2) ? c : d));
    int r = i - m*18432;
    f32x4 a0 = *(const f32x4*)&s[(size_t)r*8];
    f32x4 a1 = *(const f32x4*)&s[(size_t)r*8 + 4];
    u16x8 p;
    #pragma unroll
    for (int j = 0; j < 4; ++j) { p[j] = f2bf(a0[j]); p[j+4] = f2bf(a1[j]); }
    *(u16x8*)&dst[(size_t)i*8] = p;
}

__global__ __launch_bounds__(256) void cvt_bias(
    const float* __restrict__ a, const float* __restrict__ b,
    const float* __restrict__ c, const float* __restrict__ d,
    float* __restrict__ dst) {
    int i = blockIdx.x*256 + threadIdx.x;
    if (i >= 4*NC) return;
    int m = i / NC, r = i - m*NC;
    dst[i] = ((m==0) ? a : ((m==1) ? b : ((m==2) ? c : d)))[r];
}

__global__ __launch_bounds__(256) void prep_w(
    const float* __restrict__ qw, const float* __restrict__ kw, const float* __restrict__ vw,
    float* __restrict__ wt)   // [3][9][NC]
{
    int i = blockIdx.x*256 + threadIdx.x;
    if (i >= 3*9*NC) return;
    int m = i / (9*NC); int r = i - m*(9*NC);
    int tap = r / NC; int c = r - tap*NC;
    const float* src = (m==0) ? qw : ((m==1) ? kw : vw);
    wt[i] = src[c*9 + tap];
}

// ---------- GEMM: 256x128 tile, BK=64, 8 waves (4x2), XOR-swizzled LDS ----------
template<bool OUT_F32>
__global__ __launch_bounds__(512) void gemm_bt_bf(
    const unsigned short* __restrict__ A,
    const unsigned short* __restrict__ Wall,  // [nmat][384*384] bf16
    const float* __restrict__ Ball,           // [nmat][384] f32
    unsigned short* __restrict__ Oa, unsigned short* __restrict__ Ob, unsigned short* __restrict__ Oc,
    float* __restrict__ Of,
    int ntiles)
{
    __shared__ unsigned short lA[256*64];   // 32 KB
    __shared__ unsigned short lW[128*64];   // 16 KB
    char* lAb = (char*)lA;
    char* lWb = (char*)lW;
    const int bid = blockIdx.x;
    const int nt = bid % ntiles;      // nt-major: A-tile reuse temporally local
    const int mt = bid / ntiles;
    const int mat = nt / 3;
    const int ncol = nt - mat*3;
    const unsigned short* W = Wall + (size_t)mat*NC*NC;
    const float* Bsel = Ball + mat*NC;
    unsigned short* Osel = (mat==0) ? Oa : ((mat==1) ? Ob : Oc);
    const int Mbase = mt*256, Nbase = ncol*128;
    const int t = threadIdx.x;
    const int w = t >> 6, l = t & 63;
    const int wr = w >> 1, wc = w & 1;       // wr 0..3, wc 0..1
    const int lr = l & 15, lg = l >> 4;
    const int swg = (lr & 7) << 4;

    f32x4 acc[4][4] = {};
    for (int kt = 0; kt < 6; ++kt) {
        __syncthreads();
        #pragma unroll
        for (int i = 0; i < 4; ++i) {        // A: 2048 chunks of 16B
            int c = i*512 + t;
            int row = c >> 3, c8 = c & 7;
            int sdst = row*128 + ((c8*16) ^ ((row & 7) << 4));
            *(u16x8*)(lAb + sdst) = *(const u16x8*)&A[(size_t)(Mbase+row)*NC + kt*64 + c8*8];
        }
        #pragma unroll
        for (int i = 0; i < 2; ++i) {        // W: 1024 chunks
            int c = i*512 + t;
            int row = c >> 3, c8 = c & 7;
            int sdst = row*128 + ((c8*16) ^ ((row & 7) << 4));
            *(u16x8*)(lWb + sdst) = *(const u16x8*)&W[(size_t)(Nbase+row)*NC + kt*64 + c8*8];
        }
        __syncthreads();
        #pragma unroll
        for (int kk = 0; kk < 2; ++kk) {
            s16x8 af[4], bfr[4];
            #pragma unroll
            for (int m = 0; m < 4; ++m)
                af[m] = *(const s16x8*)(lAb + (wr*64 + m*16 + lr)*128 + ((kk*64 + lg*16) ^ swg));
            #pragma unroll
            for (int n = 0; n < 4; ++n)
                bfr[n] = *(const s16x8*)(lWb + (wc*64 + n*16 + lr)*128 + ((kk*64 + lg*16) ^ swg));
            #pragma unroll
            for (int m = 0; m < 4; ++m)
                #pragma unroll
                for (int n = 0; n < 4; ++n)
                    acc[m][n] = __builtin_amdgcn_mfma_f32_16x16x32_bf16(af[m], bfr[n], acc[m][n], 0, 0, 0);
        }
    }
    #pragma unroll
    for (int n = 0; n < 4; ++n) {
        int col = Nbase + wc*64 + n*16 + lr;
        float bias = Bsel[col];
        #pragma unroll
        for (int m = 0; m < 4; ++m) {
            int row0 = Mbase + wr*64 + m*16 + lg*4;
            #pragma unroll
            for (int r = 0; r < 4; ++r) {
                float vv = acc[m][n][r] + bias;
                if (OUT_F32) Of[(size_t)(row0 + r)*NC + col] = vv;
                else Osel[(size_t)(row0 + r)*NC + col] = f2bf(vv);
            }
        }
    }
}

// ---------- depthwise conv ----------
// MODE: 0 = token layout (b,tok,384); 1 = head-packed K (bh,tok,64); 2 = transposed V (bh,d,tok)
template<int S, int HO, int WO, bool SCALE, int MODE>
__global__ __launch_bounds__(256) void dwconv(
    const unsigned short* __restrict__ in,
    const float* __restrict__ wt9,   // (9, NC) transposed
    const float* __restrict__ bias,  // (NC)
    unsigned short* __restrict__ outp)
{
    const int nc8 = NC/8;
    int idx = blockIdx.x*256 + threadIdx.x;
    if (idx >= NB*HO*WO*nc8) return;
    int c8 = idx % nc8; int rest = idx / nc8;
    int wo = rest % WO; rest /= WO;
    int ho = rest % HO; int b = rest / HO;
    int c0 = c8*8;
    f32x4 b0 = *(const f32x4*)&bias[c0];
    f32x4 b1 = *(const f32x4*)&bias[c0+4];
    float acc[8];
    #pragma unroll
    for (int j = 0; j < 4; ++j) { acc[j] = b0[j]; acc[j+4] = b1[j]; }
    #pragma unroll
    for (int kh = 0; kh < 3; ++kh) {
        int h = ho*S + kh - 1;
        if (h < 0 || h >= HH) continue;
        #pragma unroll
        for (int kw = 0; kw < 3; ++kw) {
            int ww = wo*S + kw - 1;
            if (ww < 0 || ww >= WW0) continue;
            int tap = kh*3 + kw;
            u16x8 xv = *(const u16x8*)&in[((size_t)b*(HH*WW0) + h*WW0 + ww)*NC + c0];
            f32x4 w0 = *(const f32x4*)&wt9[tap*NC + c0];
            f32x4 w1 = *(const f32x4*)&wt9[tap*NC + c0 + 4];
            #pragma unroll
            for (int j = 0; j < 4; ++j) {
                acc[j]   += bf2f(xv[j])   * w0[j];
                acc[j+4] += bf2f(xv[j+4]) * w1[j];
            }
        }
    }
    if (SCALE) {
        #pragma unroll
        for (int j = 0; j < 8; ++j) acc[j] *= QSCALE;
    }
    int tok = ho*WO + wo;
    int hh = c0 >> 6, d0 = c0 & 63;
    if (MODE == 0) {
        u16x8 ov;
        #pragma unroll
        for (int j = 0; j < 8; ++j) ov[j] = f2bf(acc[j]);
        *(u16x8*)&outp[((size_t)b*(HO*WO) + tok)*NC + c0] = ov;
    } else if (MODE == 1) {
        u16x8 ov;
        #pragma unroll
        for (int j = 0; j < 8; ++j) ov[j] = f2bf(acc[j]);
        *(u16x8*)&outp[((size_t)(b*NHEAD + hh)*(HO*WO) + tok)*HDIM + d0] = ov;
    } else {
        size_t base = ((size_t)(b*NHEAD + hh)*HDIM + d0)*(HO*WO) + tok;
        #pragma unroll
        for (int j = 0; j < 8; ++j)
            outp[base + (size_t)j*(HO*WO)] = f2bf(acc[j]);
    }
}

// ---------- attention (proven structure; raw v_exp_f32 via builtin) ----------
// sign(s)*softmax(|s|), no max tracking, per-lane deferred denominator.
// 4 waves/block, 128 q rows/block, KVBLK=64; LDS-staged double-buffered K/V,
// reg-staged issue-early/write-late; XOR swizzle byte^=((row&7)<<4).
__global__ __launch_bounds__(256) void attn_fwd(
    const unsigned short* __restrict__ Q,   // (NB, 3136, 384) bf16 pre-scaled by 0.125*log2e
    const unsigned short* __restrict__ Kpk, // (48, 784, 64) bf16 head-packed
    const unsigned short* __restrict__ Vt,  // (48, 64, 784) bf16 transposed
    unsigned short* __restrict__ ctx)       // (NB, 3136, 384) bf16
{
    __shared__ unsigned short lK[2][4096];
    __shared__ unsigned short lV[2][4096];
    const int bid = blockIdx.x;             // 1200 = 8 XCD * 6 bh * 25 qt
    const int xcd = bid & 7, slot = bid >> 3;
    const int bh = xcd*6 + slot/25;
    const int qt = slot % 25;
    const int b = bh / NHEAD, h = bh - b*NHEAD;
    const int t = threadIdx.x;
    const int w = t >> 6, l = t & 63;
    const int lq = l & 15, lg = l >> 4;
    const int wq0 = qt*128 + w*32;
    const int wq0c = (wq0 > NQTOK-32) ? (NQTOK-32) : wq0;   // clamp: all waves run barriers

    const unsigned short* Qb = Q + ((size_t)b*NQTOK + wq0c + lq)*NC + h*HDIM;
    s16x8 qA[2][2];
    qA[0][0] = *(const s16x8*)&Qb[lg*8];
    qA[0][1] = *(const s16x8*)&Qb[32 + lg*8];
    qA[1][0] = *(const s16x8*)&Qb[16*NC + lg*8];
    qA[1][1] = *(const s16x8*)&Qb[16*NC + 32 + lg*8];

    const char* Kg = (const char*)(Kpk + (size_t)bh*NKTOK*HDIM);
    const char* Vg = (const char*)(Vt + (size_t)bh*HDIM*NKTOK);
    char* lKb = (char*)lK;
    char* lVb = (char*)lV;

    // staging: 512 x 16B chunks per 8KB tile; two K-chunks + two V-chunks per thread
    const int cr0 = t >> 3;           // rows 0..31
    const int cr1 = cr0 + 32;         // rows 32..63
    const int cc  = (t & 7) * 16;     // byte col in 128B row
    const int dst0 = cr0*128 + (cc ^ ((cr0 & 7) << 4));
    const int dst1 = cr1*128 + (cc ^ ((cr1 & 7) << 4));

    uint4 rk0, rk1, rv0, rv1;
    #define LOADT(kb) do { \
        rk0 = *(const uint4*)(Kg + (size_t)((kb) + cr0)*128 + cc); \
        rk1 = *(const uint4*)(Kg + (size_t)((kb) + cr1)*128 + cc); \
        rv0 = *(const uint4*)(Vg + (size_t)cr0*1568 + (kb)*2 + cc); \
        rv1 = *(const uint4*)(Vg + (size_t)cr1*1568 + (kb)*2 + cc); \
    } while(0)
    #define WRITET(buf) do { \
        *(uint4*)(lKb + (buf)*8192 + dst0) = rk0; \
        *(uint4*)(lKb + (buf)*8192 + dst1) = rk1; \
        *(uint4*)(lVb + (buf)*8192 + dst0) = rv0; \
        *(uint4*)(lVb + (buf)*8192 + dst1) = rv1; \
    } while(0)

    const int swc = (lq & 7) << 4;
    const int ck0 = (lg*16) ^ swc;          // K frag half 0, byte col
    const int ck1 = (64 + lg*16) ^ swc;     // K frag half 1

    float ls[2] = {0.f, 0.f};
    f32x4 oacc[2][4] = {};

    LOADT(0);
    WRITET(0);
    __syncthreads();

    for (int kt = 0; kt < 12; ++kt) {
        const int cur = kt & 1;
        if (kt < 11) LOADT((kt+1)*64);
        const char* Kl = lKb + cur*8192;
        const char* Vl = lVb + cur*8192;
        f32x4 st[2][4] = {};
        __builtin_amdgcn_s_setprio(1);
        #pragma unroll
        for (int kfr = 0; kfr < 4; ++kfr) {
            int rb = (kfr*16 + lq)*128;
            s16x8 kf0 = *(const s16x8*)(Kl + rb + ck0);
            s16x8 kf1 = *(const s16x8*)(Kl + rb + ck1);
            st[0][kfr] = __builtin_amdgcn_mfma_f32_16x16x32_bf16(kf0, qA[0][0], st[0][kfr], 0,0,0);
            st[0][kfr] = __builtin_amdgcn_mfma_f32_16x16x32_bf16(kf1, qA[0][1], st[0][kfr], 0,0,0);
            st[1][kfr] = __builtin_amdgcn_mfma_f32_16x16x32_bf16(kf0, qA[1][0], st[1][kfr], 0,0,0);
            st[1][kfr] = __builtin_amdgcn_mfma_f32_16x16x32_bf16(kf1, qA[1][1], st[1][kfr], 0,0,0);
        }
        __builtin_amdgcn_s_setprio(0);
        s16x4 pbv[2][4];
        #pragma unroll
        for (int qf = 0; qf < 2; ++qf) {
            float rs = 0.f;
            #pragma unroll
            for (int kfr = 0; kfr < 4; ++kfr)
                #pragma unroll
                for (int r = 0; r < 4; ++r) {
                    float s = st[qf][kfr][r];
                    float e = __builtin_amdgcn_exp2f(fabsf(s));
                    rs += e;
                    pbv[qf][kfr][r] = (short)f2bf_rn(copysignf(e, s));
                }
            ls[qf] += rs;
        }
        __builtin_amdgcn_s_setprio(1);
        #pragma unroll
        for (int ks = 0; ks < 4; ++ks)
            #pragma unroll
            for (int f = 0; f < 4; ++f) {
                int va = (f*16 + lq)*128 + ((ks*32 + lg*8) ^ swc);
                s16x4 vvf = *(const s16x4*)(Vl + va);
                oacc[0][f] = __builtin_amdgcn_mfma_f32_16x16x16bf16_1k(vvf, pbv[0][ks], oacc[0][f], 0,0,0);
                oacc[1][f] = __builtin_amdgcn_mfma_f32_16x16x16bf16_1k(vvf, pbv[1][ks], oacc[1][f], 0,0,0);
            }
        __builtin_amdgcn_s_setprio(0);
        if (kt < 11) {
            WRITET(cur ^ 1);
            __syncthreads();
        }
    }
    // tail: k = 768..783 direct from global
    {
        const unsigned short* Kb2 = (const unsigned short*)Kg;
        const unsigned short* Vb2 = (const unsigned short*)Vg;
        const unsigned short* kr = &Kb2[(size_t)(768 + lq)*HDIM];
        s16x8 kf0 = *(const s16x8*)&kr[lg*8];
        s16x8 kf1 = *(const s16x8*)&kr[32 + lg*8];
        f32x4 st[2] = {};
        st[0] = __builtin_amdgcn_mfma_f32_16x16x32_bf16(kf0, qA[0][0], st[0], 0,0,0);
        st[0] = __builtin_amdgcn_mfma_f32_16x16x32_bf16(kf1, qA[0][1], st[0], 0,0,0);
        st[1] = __builtin_amdgcn_mfma_f32_16x16x32_bf16(kf0, qA[1][0], st[1], 0,0,0);
        st[1] = __builtin_amdgcn_mfma_f32_16x16x32_bf16(kf1, qA[1][1], st[1], 0,0,0);
        s16x4 vv[4];
        #pragma unroll
        for (int f = 0; f < 4; ++f)
            vv[f] = *(const s16x4*)&Vb2[(size_t)(f*16 + lq)*NKTOK + 768 + lg*4];
        s16x4 pbv[2];
        #pragma unroll
        for (int qf = 0; qf < 2; ++qf) {
            float rs = 0.f;
            #pragma unroll
            for (int r = 0; r < 4; ++r) {
                float s = st[qf][r];
                float e = __builtin_amdgcn_exp2f(fabsf(s));
                rs += e;
                pbv[qf][r] = (short)f2bf_rn(copysignf(e, s));
            }
            ls[qf] += rs;
        }
        #pragma unroll
        for (int f = 0; f < 4; ++f) {
            oacc[0][f] = __builtin_amdgcn_mfma_f32_16x16x16bf16_1k(vv[f], pbv[0], oacc[0][f], 0,0,0);
            oacc[1][f] = __builtin_amdgcn_mfma_f32_16x16x16bf16_1k(vv[f], pbv[1], oacc[1][f], 0,0,0);
        }
    }
    if (wq0 < NQTOK) {
        #pragma unroll
        for (int qf = 0; qf < 2; ++qf) {
            float lr2 = ls[qf];
            lr2 += __shfl_xor(lr2, 16);
            lr2 += __shfl_xor(lr2, 32);
            float inv = 1.f / lr2;
            unsigned short* cb = ctx + ((size_t)b*NQTOK + wq0 + qf*16 + lq)*NC + h*HDIM;
            #pragma unroll
            for (int f = 0; f < 4; ++f) {
                s16x4 o;
                #pragma unroll
                for (int r = 0; r < 4; ++r) o[r] = (short)f2bf(oacc[qf][f][r] * inv);
                *(s16x4*)&cb[f*16 + lg*4] = o;
            }
        }
    }
    #undef LOADT
    #undef WRITET
}

extern "C" void kernel_launch(void* const* d_in, const int* in_sizes, int n_in,
                              void* d_out, int out_size, void* d_ws, size_t ws_size,
                              hipStream_t stream)
{
    (void)in_sizes; (void)n_in; (void)out_size; (void)ws_size;
    const float* x      = (const float*)d_in[0];
    const float* q_w    = (const float*)d_in[3];
    const float* q_b    = (const float*)d_in[4];
    const float* k_w    = (const float*)d_in[5];
    const float* k_b    = (const float*)d_in[6];
    const float* v_w    = (const float*)d_in[7];
    const float* v_b    = (const float*)d_in[8];
    const float* q_dw_w = (const float*)d_in[9];
    const float* q_dw_b = (const float*)d_in[10];
    const float* k_dw_w = (const float*)d_in[11];
    const float* k_dw_b = (const float*)d_in[12];
    const float* v_dw_w = (const float*)d_in[13];
    const float* v_dw_b = (const float*)d_in[14];
    const float* proj_w = (const float*)d_in[15];
    const float* proj_b = (const float*)d_in[16];
    float* outf = (float*)d_out;
    unsigned short* ws  = (unsigned short*)d_ws;

    const size_t nQ  = (size_t)NB*NQTOK*NC;   // 9,633,792 elems
    const size_t nKc = (size_t)NB*NKTOK*NC;   // 2,408,448 elems
    unsigned short* preQ = ws;                // bf16 pre-conv Q
    unsigned short* preK = ws + nQ;           // bf16 pre-conv K; later ctx
    unsigned short* Kpk  = ws + 2*nQ;         // bf16 post-conv K, head-packed (bh,k,64)
    unsigned short* Vt   = Kpk + nKc;         // bf16 post-conv V, transposed (bh,d,k)
    unsigned short* wbf  = Vt + nKc;          // bf16 [4][384*384] dense weights
    float* wtab = (float*)(wbf + (size_t)4*NC*NC);   // [3][9][384] dw weights transposed
    float* ball = wtab + 3*9*NC;              // [4][384] biases
    unsigned short* preV = (unsigned short*)d_out;          // d_out lower half
    unsigned short* Qc   = (unsigned short*)d_out;          // after preV consumed
    unsigned short* xbf  = ((unsigned short*)d_out) + nQ;   // d_out upper half: bf16 x
    unsigned short* ctx  = preK;              // reuse preK after k-conv

    // 0. prep: dtype conversions + weight transposes
    cvt_bf16<<<dim3(4704), dim3(256), 0, stream>>>(x, xbf, (int)(nQ/8));
    cvt_w4  <<<dim3(288),  dim3(256), 0, stream>>>(q_w, k_w, v_w, proj_w, wbf);
    cvt_bias<<<dim3(6),    dim3(256), 0, stream>>>(q_b, k_b, v_b, proj_b, ball);
    prep_w  <<<dim3(41),   dim3(256), 0, stream>>>(q_dw_w, k_dw_w, v_dw_w, wtab);
    // 1. QKV projections (bf16 x bf16), 256x128 tiles: Q->preQ, K->preK, V->preV(d_out)
    gemm_bt_bf<false><<<dim3(98*9), dim3(512), 0, stream>>>(
        xbf, wbf, ball, preQ, preK, preV, nullptr, 9);
    // 2. depthwise convs; K head-packed, V transposed, Q scaled by 0.125*log2e
    dwconv<2,28,28,false,1><<<dim3(1176), dim3(256), 0, stream>>>(preK, wtab + 1*9*NC, k_dw_b, Kpk);
    dwconv<2,28,28,false,2><<<dim3(1176), dim3(256), 0, stream>>>(preV, wtab + 2*9*NC, v_dw_b, Vt);
    dwconv<1,56,56,true ,0><<<dim3(4704), dim3(256), 0, stream>>>(preQ, wtab + 0*9*NC, q_dw_b, Qc);
    // 3. attention: 1200 = 48 bh x 25 q-tiles of 128
    attn_fwd<<<dim3(1200), dim3(256), 0, stream>>>(Qc, Kpk, Vt, ctx);
    // 4. output projection (256x128 tiles) -> f32 d_out
    gemm_bt_bf<true><<<dim3(98*3), dim3(512), 0, stream>>>(
        ctx, wbf + (size_t)3*NC*NC, ball + 3*NC, nullptr, nullptr, nullptr, outf, 3);
}